// Round 5
// baseline (163.354 us; speedup 1.0000x reference)
//
#include <hip/hip_runtime.h>

// retinex_synthesis, SINGLE-kernel rolling separable blur.
// out = clip((1+ins)*exp(blur(log1p(bg) - log1p(ins))) - 1, 0, 1)
//
// R10 = R9 body, 128-tall tiles (clean occupancy retry).
// R9 post-mortem: LDS-only barriers were NEUTRAL (63us) -> barrier vmcnt
// drain was not the stall. Kernel sits at 63us vs 27us HBM floor / ~19us
// VALU floor with VALUBusy 58%, occupancy 24.5% (3 waves/SIMD): stall-
// bound with too little TLP. R6's 128-tall attempt regressed for reasons
// now FIXED: (a) cross-barrier insv liveness spilled (WRITE 49152->55296;
// R9 loads ins inside the emit phase, VGPR 44, no spill), (b) win[40]
// h-blur liveness (now streaming). Retry 128-tall on the clean base:
// grid 8*4*48 = 1536 blocks, LDS 30.2KB -> 5 blocks/CU = 20 waves/CU
// (5 waves/SIMD, +67% TLP). Known cost: +11% stage/hblur work (5 chunks
// per 4 emitting vs 9/8), +~15MB y-halo FETCH. Tripwire: WRITE_SIZE must
// stay exactly 49152 KB (no spill). If this regresses anyway, occupancy
// hypothesis is dead -> R11 goes after VALU issue count (pk-f32).
//
// Per chunk k (k=0..4): stage chunk k (rows [32k-15,32k+17), 96 cols)
// from PREFETCHED regs -> LDS; prefetch chunk k+1; [lgkm bar];
// h-blur -> 64-row ring; [lgkm bar]; emit rows [32(k-1),32k) by v-blur
// + fused epilogue ((1+ins)*exp(acc)-1, ins loaded in-phase, L2-hot).
// Ring retention window [32k-47,32k+17) covers emission [32k-47,32k+14];
// every overwrite/read pair is barrier-separated. Barriers are LDS-only
// (lgkmcnt(0) + s_barrier): all cross-wave hazards are LDS; prefetch
// stays in flight across barriers, vmcnt waits at first use.
// h-blur streaming (R7): float4 accumulated straight into o[8].
// Emit ring addressing wave-uniform via readfirstlane -> SALU.

constexpr int W_ = 512, H_ = 512, NIMG = 48;
constexpr int TH = 128;             // output rows per block
constexpr int NCH = TH / 32 + 1;    // 5 chunks (first is halo fill)
constexpr int SPITCH = 100;  // staging pitch: 96 cols + 4; 25 slots, 25%8==1
constexpr int RPITCH = 68;   // ring pitch: 64 cols + 4; 17 slots, 17%8==1

// LDS-only barrier: cross-wave LDS visibility needs lgkmcnt(0) commit, but
// NOT vmcnt drain (that's the __syncthreads tax this kernel avoids).
#define LDS_BARRIER()                                      \
  do {                                                     \
    asm volatile("" ::: "memory");                         \
    asm volatile("s_waitcnt lgkmcnt(0)" ::: "memory");     \
    __builtin_amdgcn_s_barrier();                          \
    asm volatile("" ::: "memory");                         \
  } while (0)

__device__ constexpr float G[31] = {
    8.8805851e-04f, 1.5861066e-03f, 2.7217699e-03f, 4.4874399e-03f,
    7.1084368e-03f, 1.0818767e-02f, 1.5820117e-02f, 2.2226435e-02f,
    3.0002549e-02f, 3.8911209e-02f, 4.8486352e-02f, 5.8048702e-02f,
    6.6771901e-02f, 7.3794364e-02f, 7.8357552e-02f, 7.9940480e-02f,
    7.8357552e-02f, 7.3794364e-02f, 6.6771901e-02f, 5.8048702e-02f,
    4.8486352e-02f, 3.8911209e-02f, 3.0002549e-02f, 2.2226435e-02f,
    1.5820117e-02f, 1.0818767e-02f, 7.1084368e-03f, 4.4874399e-03f,
    2.7217699e-03f, 1.5861066e-03f, 8.8805851e-04f};

__global__ __launch_bounds__(256, 5) void retinex_roll(const float* __restrict__ bg,
                                                       const float* __restrict__ ins,
                                                       float* __restrict__ out) {
  __shared__ __align__(16) float sd[32 * SPITCH];  // 12,800 B: staged d chunk
  __shared__ __align__(16) float hr[64 * RPITCH];  // 17,408 B: h-blurred ring

  const int tid  = threadIdx.x;
  const int lane = tid & 63;
  const int x0 = blockIdx.x * 64;
  const int y0 = blockIdx.y * TH;
  const size_t base = (size_t)blockIdx.z * (size_t)(H_ * W_);

  // Staging geometry (k-invariant): 768 float4 items = 32 rows x 24 slots.
  int sr[3], sc[3], gx[3]; bool okx[3];
#pragma unroll
  for (int s = 0; s < 3; ++s) {
    const int item = tid + 256 * s;
    sr[s] = item / 24;
    sc[s] = item - 24 * sr[s];
    gx[s] = x0 - 16 + 4 * sc[s];          // float4-aligned; OOB is whole-float4
    okx[s] = (unsigned)gx[s] < (unsigned)W_;
  }
  const int hrow = tid >> 3;              // h-blur: staged row 0..31
  const int hcg  = tid & 7;               // h-blur: col group (8 cols each)
  // emit row-group 0..3 — wave-uniform: force scalar so ring addressing is SALU
  const int eg = __builtin_amdgcn_readfirstlane(tid >> 6);

  // Initial prefetch: chunk 0 = rows y0-15 .. y0+16.
  float4 pb[3], pn[3];
#pragma unroll
  for (int s = 0; s < 3; ++s) {
    const int gy = y0 - 15 + sr[s];
    pb[s] = make_float4(0.f, 0.f, 0.f, 0.f);
    pn[s] = pb[s];
    if (okx[s] && (unsigned)gy < (unsigned)H_) {
      const size_t a = base + (size_t)gy * W_ + gx[s];
      pb[s] = *(const float4*)(bg + a);
      pn[s] = *(const float4*)(ins + a);
    }
  }

#pragma unroll 1
  for (int k = 0; k < NCH; ++k) {
    // ---- Stage chunk k from prefetched registers: d = log1p(bg)-log1p(ins).
#pragma unroll
    for (int s = 0; s < 3; ++s) {
      float4 v;
      v.x = __logf(1.f + pb[s].x) - __logf(1.f + pn[s].x);
      v.y = __logf(1.f + pb[s].y) - __logf(1.f + pn[s].y);
      v.z = __logf(1.f + pb[s].z) - __logf(1.f + pn[s].z);
      v.w = __logf(1.f + pb[s].w) - __logf(1.f + pn[s].w);
      *(float4*)(sd + sr[s] * SPITCH + 4 * sc[s]) = v;   // slot%8=(sr+sc)%8
    }
    // ---- Prefetch chunk k+1; loads stay in flight until next iteration's
    //      stage (vmcnt wait at first USE, not at the barriers).
    if (k < NCH - 1) {
#pragma unroll
      for (int s = 0; s < 3; ++s) {
        const int gy = y0 + 32 * (k + 1) - 15 + sr[s];
        float4 b0 = make_float4(0.f, 0.f, 0.f, 0.f), n0 = b0;
        if (okx[s] && (unsigned)gy < (unsigned)H_) {
          const size_t a = base + (size_t)gy * W_ + gx[s];
          b0 = *(const float4*)(bg + a);
          n0 = *(const float4*)(ins + a);
        }
        pb[s] = b0; pn[s] = n0;
      }
    }
    LDS_BARRIER();   // A: sd ready; also orders prev emit's hr reads vs h-blur writes

    // ---- H-blur staged row `hrow`, output cols 8*hcg..8*hcg+7 -> ring.
    //      STREAMING: accumulate each loaded float4 straight into o[8].
    {
      float o[8];
#pragma unroll
      for (int e = 0; e < 8; ++e) o[e] = 0.f;
      const float4* p4 = (const float4*)(sd + hrow * SPITCH) + 2 * hcg;
#pragma unroll
      for (int q = 0; q < 10; ++q) {       // slot%8=(hrow+2hcg+q)%8: balanced
        const float4 v = p4[q];
        const float w[4] = {v.x, v.y, v.z, v.w};
#pragma unroll
        for (int t = 0; t < 4; ++t) {
          const int pos = 4 * q + t;       // window index: sd col 8*hcg + pos
#pragma unroll
          for (int e = 0; e < 8; ++e) {
            const int c = pos - 1 - e;     // compile-time
            if (c >= 0 && c < 31) o[e] += G[c] * w[t];
          }
        }
      }
      const int slot = (32 * k - 15 + hrow + 128) & 63;  // logical row 32k-15+hrow
      float* dst = hr + slot * RPITCH + 8 * hcg;
      *(float4*)(dst)     = make_float4(o[0], o[1], o[2], o[3]);
      *(float4*)(dst + 4) = make_float4(o[4], o[5], o[6], o[7]);
    }
    LDS_BARRIER();   // B: ring rows for this chunk ready

    // ---- Emit output rows [32(k-1), 32k): v-blur from ring + epilogue.
    if (k >= 1) {
      const int t0 = 32 * (k - 1) + 8 * eg;    // block-relative first output row
      // Issue epilogue ins loads NOW (L2-hot, staged ~1 chunk ago); their
      // latency hides under the 38-step v-blur. Same phase -> no spill.
      float insv[8];
#pragma unroll
      for (int p = 0; p < 8; ++p)
        insv[p] = ins[base + (size_t)(y0 + t0 + p) * W_ + x0 + lane];
      float acc[8];
#pragma unroll
      for (int p = 0; p < 8; ++p) acc[p] = 0.f;
#pragma unroll
      for (int j = 0; j < 38; ++j) {
        const int row = (t0 - 15 + j + 128) & 63;        // scalar (SALU)
        const float v = hr[row * RPITCH + lane];         // lane-consecutive
#pragma unroll
        for (int p = 0; p < 8; ++p) {
          const int c = j - p;
          if (c >= 0 && c < 31) acc[p] += G[c] * v;
        }
      }
#pragma unroll
      for (int p = 0; p < 8; ++p) {
        const size_t a = base + (size_t)(y0 + t0 + p) * W_ + x0 + lane;
        // expm1(log1p(ins) + acc) == (1+ins)*exp(acc) - 1
        float r = (1.f + insv[p]) * __expf(acc[p]) - 1.f;
        out[a] = fminf(fmaxf(r, 0.f), 1.f);
      }
    }
  }
}

extern "C" void kernel_launch(void* const* d_in, const int* in_sizes, int n_in,
                              void* d_out, int out_size, void* d_ws, size_t ws_size,
                              hipStream_t stream) {
  const float* bg  = (const float*)d_in[0];
  const float* ins = (const float*)d_in[1];
  float* out = (float*)d_out;
  retinex_roll<<<dim3(8, 4, NIMG), dim3(256), 0, stream>>>(bg, ins, out);
}

// Round 6
// 151.892 us; speedup vs baseline: 1.0755x; 1.0755x over previous
//
#include <hip/hip_runtime.h>

// retinex_synthesis, SINGLE-kernel rolling separable blur.
// out = clip((1+ins)*exp2(blur(log2(1+bg) - log2(1+ins))) - 1, 0, 1)
//   (log2 domain: blur is linear, so exp(blur(ln-diff)) == exp2(blur(log2-
//    diff)) -- raw v_log_f32/v_exp_f32, no ln2/1.4427 scale muls at all)
//
// R11 = R9 base (256-tall, proven 63us) + PACKED-F32 blur FMAs + log2 domain.
// R10 post-mortem: occupancy 24.5->35% with VALUBusy flat at 59% and time
// +11% (= extra halo work) -> NOT latency-bound; occupancy hypothesis dead.
// Correct arithmetic: 62 FMA/px separable blur = ~32us of pure scalar FMA
// issue (> 27us HBM floor) -> the kernel is VALU-ISSUE-bound and the 496
// v_fmac_f32 per thread-chunk are the dominant class. Fix: v_pk_fma_f32
// (gfx90a+ full-rate packed f32; LLVM selects it for <2 x float> fma).
// Both blur loops packed across output pairs (p0,p1),(p2,p3),...:
// coefficient pairs {G[c],G[c-1]} are compile-time, zero-padded at window
// edges (fma(v,0,acc) exact; per-output accumulation order UNCHANGED ->
// blur bitwise identical). 496 scalar FMA -> 256 pk FMA per thread-chunk.
//
// Geometry (proven): 64w x 256t strips, grid 8*2*48 = 768 = 3 blocks/CU.
// 9 chunks of 32 rows: stage chunk k (rows [32k-15,32k+17), 96 cols) from
// PREFETCHED regs -> LDS; prefetch k+1; [lgkm bar]; h-blur -> 64-row ring;
// [lgkm bar]; emit rows [32(k-1),32k) v-blur + fused epilogue.
// Barriers are LDS-only (lgkmcnt(0)+s_barrier, R9): all cross-wave hazards
// are LDS; prefetch stays in flight across barriers.
// Emit ring addressing wave-uniform via readfirstlane -> SALU.

constexpr int W_ = 512, H_ = 512, NIMG = 48;
constexpr int SPITCH = 100;  // staging pitch: 96 cols + 4; 25 slots, 25%8==1
constexpr int RPITCH = 68;   // ring pitch: 64 cols + 4; 17 slots, 17%8==1

typedef float v2f __attribute__((ext_vector_type(2)));

// LDS-only barrier: cross-wave LDS visibility needs lgkmcnt(0) commit, but
// NOT vmcnt drain (that's the __syncthreads tax this kernel avoids).
#define LDS_BARRIER()                                      \
  do {                                                     \
    asm volatile("" ::: "memory");                         \
    asm volatile("s_waitcnt lgkmcnt(0)" ::: "memory");     \
    __builtin_amdgcn_s_barrier();                          \
    asm volatile("" ::: "memory");                         \
  } while (0)

__device__ constexpr float G[31] = {
    8.8805851e-04f, 1.5861066e-03f, 2.7217699e-03f, 4.4874399e-03f,
    7.1084368e-03f, 1.0818767e-02f, 1.5820117e-02f, 2.2226435e-02f,
    3.0002549e-02f, 3.8911209e-02f, 4.8486352e-02f, 5.8048702e-02f,
    6.6771901e-02f, 7.3794364e-02f, 7.8357552e-02f, 7.9940480e-02f,
    7.8357552e-02f, 7.3794364e-02f, 6.6771901e-02f, 5.8048702e-02f,
    4.8486352e-02f, 3.8911209e-02f, 3.0002549e-02f, 2.2226435e-02f,
    1.5820117e-02f, 1.0818767e-02f, 7.1084368e-03f, 4.4874399e-03f,
    2.7217699e-03f, 1.5861066e-03f, 8.8805851e-04f};

// Zero-padded coefficient: compile-time c -> literal (0 outside [0,31)).
__device__ constexpr float gc(int c) { return (c >= 0 && c < 31) ? G[c] : 0.f; }

__global__ __launch_bounds__(256, 3) void retinex_roll(const float* __restrict__ bg,
                                                       const float* __restrict__ ins,
                                                       float* __restrict__ out) {
  __shared__ __align__(16) float sd[32 * SPITCH];  // 12,800 B: staged d chunk
  __shared__ __align__(16) float hr[64 * RPITCH];  // 17,408 B: h-blurred ring

  const int tid  = threadIdx.x;
  const int lane = tid & 63;
  const int x0 = blockIdx.x * 64;
  const int y0 = blockIdx.y * 256;
  const size_t base = (size_t)blockIdx.z * (size_t)(H_ * W_);

  // Staging geometry (k-invariant): 768 float4 items = 32 rows x 24 slots.
  int sr[3], sc[3], gx[3]; bool okx[3];
#pragma unroll
  for (int s = 0; s < 3; ++s) {
    const int item = tid + 256 * s;
    sr[s] = item / 24;
    sc[s] = item - 24 * sr[s];
    gx[s] = x0 - 16 + 4 * sc[s];          // float4-aligned; OOB is whole-float4
    okx[s] = (unsigned)gx[s] < (unsigned)W_;
  }
  const int hrow = tid >> 3;              // h-blur: staged row 0..31
  const int hcg  = tid & 7;               // h-blur: col group (8 cols each)
  // emit row-group 0..3 — wave-uniform: force scalar so ring addressing is SALU
  const int eg = __builtin_amdgcn_readfirstlane(tid >> 6);

  // Initial prefetch: chunk 0 = rows y0-15 .. y0+16.
  float4 pb[3], pn[3];
#pragma unroll
  for (int s = 0; s < 3; ++s) {
    const int gy = y0 - 15 + sr[s];
    pb[s] = make_float4(0.f, 0.f, 0.f, 0.f);
    pn[s] = pb[s];
    if (okx[s] && (unsigned)gy < (unsigned)H_) {
      const size_t a = base + (size_t)gy * W_ + gx[s];
      pb[s] = *(const float4*)(bg + a);
      pn[s] = *(const float4*)(ins + a);
    }
  }

#pragma unroll 1
  for (int k = 0; k < 9; ++k) {
    // ---- Stage chunk k from prefetched regs: d2 = log2(1+bg)-log2(1+ins).
#pragma unroll
    for (int s = 0; s < 3; ++s) {
      float4 v;
      v.x = __builtin_amdgcn_logf(1.f + pb[s].x) - __builtin_amdgcn_logf(1.f + pn[s].x);
      v.y = __builtin_amdgcn_logf(1.f + pb[s].y) - __builtin_amdgcn_logf(1.f + pn[s].y);
      v.z = __builtin_amdgcn_logf(1.f + pb[s].z) - __builtin_amdgcn_logf(1.f + pn[s].z);
      v.w = __builtin_amdgcn_logf(1.f + pb[s].w) - __builtin_amdgcn_logf(1.f + pn[s].w);
      *(float4*)(sd + sr[s] * SPITCH + 4 * sc[s]) = v;   // slot%8=(sr+sc)%8
    }
    // ---- Prefetch chunk k+1; loads stay in flight until next iteration's
    //      stage (vmcnt wait at first USE, not at the barriers).
    if (k < 8) {
#pragma unroll
      for (int s = 0; s < 3; ++s) {
        const int gy = y0 + 32 * (k + 1) - 15 + sr[s];
        float4 b0 = make_float4(0.f, 0.f, 0.f, 0.f), n0 = b0;
        if (okx[s] && (unsigned)gy < (unsigned)H_) {
          const size_t a = base + (size_t)gy * W_ + gx[s];
          b0 = *(const float4*)(bg + a);
          n0 = *(const float4*)(ins + a);
        }
        pb[s] = b0; pn[s] = n0;
      }
    }
    LDS_BARRIER();   // A: sd ready; also orders prev emit's hr reads vs h-blur writes

    // ---- H-blur staged row `hrow`, cols 8*hcg..8*hcg+7 -> ring.
    //      PACKED: output pairs (e,e+1) accumulate via v_pk_fma_f32.
    {
      v2f o2[4];
#pragma unroll
      for (int m = 0; m < 4; ++m) o2[m] = (v2f){0.f, 0.f};
      const float4* p4 = (const float4*)(sd + hrow * SPITCH) + 2 * hcg;
#pragma unroll
      for (int q = 0; q < 10; ++q) {       // slot%8=(hrow+2hcg+q)%8: balanced
        const float4 v = p4[q];
        const float w[4] = {v.x, v.y, v.z, v.w};
#pragma unroll
        for (int t = 0; t < 4; ++t) {
          const int pos = 4 * q + t;       // window index: sd col 8*hcg + pos
          const v2f vv = {w[t], w[t]};
#pragma unroll
          for (int m = 0; m < 4; ++m) {
            const int c0 = pos - 1 - 2 * m;   // compile-time; pair valid iff
            if (c0 >= 0 && c0 < 32) {         // c0 in [0,31) or c0-1 in [0,31)
              const v2f kc = {gc(c0), gc(c0 - 1)};
              o2[m] = __builtin_elementwise_fma(vv, kc, o2[m]);
            }
          }
        }
      }
      const int slot = (32 * k - 15 + hrow + 128) & 63;  // logical row 32k-15+hrow
      float* dst = hr + slot * RPITCH + 8 * hcg;
      *(float4*)(dst)     = make_float4(o2[0].x, o2[0].y, o2[1].x, o2[1].y);
      *(float4*)(dst + 4) = make_float4(o2[2].x, o2[2].y, o2[3].x, o2[3].y);
    }
    LDS_BARRIER();   // B: ring rows for this chunk ready

    // ---- Emit output rows [32(k-1), 32k): v-blur from ring + epilogue.
    if (k >= 1) {
      const int t0 = 32 * (k - 1) + 8 * eg;    // block-relative first output row
      // Issue epilogue ins loads NOW (L2-hot, staged ~1 chunk ago); their
      // latency hides under the 38-step v-blur. Same phase -> no spill.
      float insv[8];
#pragma unroll
      for (int p = 0; p < 8; ++p)
        insv[p] = ins[base + (size_t)(y0 + t0 + p) * W_ + x0 + lane];
      v2f acc2[4];
#pragma unroll
      for (int m = 0; m < 4; ++m) acc2[m] = (v2f){0.f, 0.f};
#pragma unroll
      for (int j = 0; j < 38; ++j) {
        const int row = (t0 - 15 + j + 128) & 63;        // scalar (SALU)
        const float v = hr[row * RPITCH + lane];         // lane-consecutive
        const v2f vv = {v, v};
#pragma unroll
        for (int m = 0; m < 4; ++m) {
          const int c0 = j - 2 * m;            // compile-time; pair valid iff
          if (c0 >= 0 && c0 < 32) {            // c0 in [0,31) or c0-1 in [0,31)
            const v2f kc = {gc(c0), gc(c0 - 1)};
            acc2[m] = __builtin_elementwise_fma(vv, kc, acc2[m]);
          }
        }
      }
#pragma unroll
      for (int p = 0; p < 8; ++p) {
        const float a = (p & 1) ? acc2[p >> 1].y : acc2[p >> 1].x;
        const size_t ga = base + (size_t)(y0 + t0 + p) * W_ + x0 + lane;
        // expm1(log(1+ins) + ln2*acc) == (1+ins)*exp2(acc) - 1
        float r = (1.f + insv[p]) * __builtin_amdgcn_exp2f(a) - 1.f;
        out[ga] = fminf(fmaxf(r, 0.f), 1.f);
      }
    }
  }
}

extern "C" void kernel_launch(void* const* d_in, const int* in_sizes, int n_in,
                              void* d_out, int out_size, void* d_ws, size_t ws_size,
                              hipStream_t stream) {
  const float* bg  = (const float*)d_in[0];
  const float* ins = (const float*)d_in[1];
  float* out = (float*)d_out;
  retinex_roll<<<dim3(8, 2, NIMG), dim3(256), 0, stream>>>(bg, ins, out);
}